// Round 11
// baseline (522.374 us; speedup 1.0000x reference)
//
#include <hip/hip_runtime.h>
#include <hip/hip_bf16.h>
#include <hip/hip_fp16.h>

#define N_NODES 100000
#define N_EDGES 1600000
#define HID     64
#define LAYERS  8
#define OUT_DIM 40
#define SCAN_NB 98   // ceil(100000/1024)
#define ZROW    N_NODES  // guaranteed-zero row in t0 (pad rows written 0 every layer)
#define NBUK    196      // ceil(100000/512) buckets of 512 nodes
#define BUK_CAP 12000    // avg 8163/bucket -> huge sigma headroom
#define S1_EPB  2048     // edges per bucket1 block (256 thr x 8)
#define FU_N    64       // nodes per fused block
#define FU_CAP  2048     // staged csr entries (mean 1024, +32 sigma), 8KB LDS
#define HB_S    72       // hbuf row stride in halves (64 + 8 pad: 2-way banks, 16B aligned)

typedef __attribute__((ext_vector_type(8))) short short8;
typedef __attribute__((ext_vector_type(8))) _Float16 half8;
typedef __attribute__((ext_vector_type(4))) float float4v;
typedef __attribute__((ext_vector_type(4))) unsigned int uint4v;

// ---------- runtime environment hedges ----------
// flags[0] = 1 if feature inputs are float32 (else bf16)
// flags[1] = 1 if edge_index is int64 (else int32)
__device__ inline float ldext(const void* p, bool f32, size_t i) {
    return f32 ? ((const float*)p)[i]
               : __bfloat162float(((const __hip_bfloat16*)p)[i]);
}
__device__ inline int load_edge(const void* raw, bool is64, long long idx) {
    return is64 ? (int)((const long long*)raw)[idx] : ((const int*)raw)[idx];
}
__device__ inline unsigned short bf16bits(float v) {
    union { __hip_bfloat16 b; unsigned short u; } a;
    a.b = __float2bfloat16(v);
    return a.u;
}
__device__ inline unsigned short f16bits(float v) {
    union { __half h; unsigned short u; } a;
    a.h = __float2half_rn(v);
    return a.u;
}
__device__ inline __half2 u2h2(unsigned u) {
    union { unsigned u; __half2 h; } x; x.u = u; return x.h;
}
__device__ inline unsigned h22u(__half2 h) {
    union { unsigned u; __half2 h; } x; x.h = h; return x.u;
}

// DPP lane-rotation move (VALU pipe). 0x128 = row_ror:8 — rotation by 8 within a
// 16-lane row == pairwise xor-8 exchange (valid for commutative sum).
template <int CTRL>
__device__ inline unsigned dppu(unsigned v) {
    return (unsigned)__builtin_amdgcn_update_dpp((int)v, (int)v, CTRL, 0xF, 0xF, false);
}

// inline-asm 16B gather: SGPR base (wave-uniform t0 ptr) + 32b per-lane voffset.
// asm volatile ordering pins the 4-deep pipeline at ISA level.
__device__ inline uint4v gload16(const __half* base, unsigned voff) {
    uint4v d;
    asm volatile("global_load_dwordx4 %0, %1, %2"
                 : "=v"(d)
                 : "v"(voff), "s"((unsigned long long)base));
    return d;
}
// counted wait + scheduler fence (rule #18: VALU consumers must not hoist above it)
#define WAITV(N) do { asm volatile("s_waitcnt vmcnt(" #N ")" ::: "memory"); \
                      __builtin_amdgcn_sched_barrier(0); } while (0)

// also zeroes gcur (fused former zero_int_kernel)
__global__ void detect_kernel(const void* x, const void* ei, int* flags, int* gcur) {
    int t = threadIdx.x;  // 64 threads
    for (int i = t; i < NBUK; i += 64) gcur[i] = 0;
    float v = fabsf(__bfloat162float(((const __hip_bfloat16*)x)[t]));
    bool inband = (v >= 0.00390625f && v <= 16.0f);
    unsigned long long m = __ballot(inband);
    if (t == 0) {
        flags[0] = (__popcll(m) < 48) ? 1 : 0;  // fp32 misread as bf16 -> ~33/64 in band
        const int* e32 = (const int*)ei;
        flags[1] = ((e32[1] | e32[3] | e32[5] | e32[7]) == 0) ? 1 : 0;
    }
}

// pack: bias (fp32); W0 as bf16 MFMA B-frags; W1..7 and lwB as f16 MFMA B-frags.
__global__ __launch_bounds__(256) void pack_params_kernel(const void* bs, const void* lin_w,
                                                          const void* W0, const void* Ws,
                                                          const int* __restrict__ flags,
                                                          float* __restrict__ bsf,
                                                          unsigned short* __restrict__ wpack) {
    bool f32 = flags[0] != 0;
    int gid = blockIdx.x * 256 + threadIdx.x;
    int stride = gridDim.x * 256;
    for (int idx = gid; idx < LAYERS * HID; idx += stride) bsf[idx] = ldext(bs, f32, idx);
    // layer 0 W: K=128 (KS=4), 8192 elements, bf16 (A = x is bf16)
    for (int idx = gid; idx < 8192; idx += stride) {
        int j = idx & 7, lane = (idx >> 3) & 63, rest = idx >> 9;
        int ks = rest & 3, ct = rest >> 2;
        int quad = lane >> 4, m = lane & 15;
        wpack[idx] = bf16bits(ldext(W0, f32, (size_t)(ks * 32 + quad * 8 + j) * 64 + ct * 16 + m));
    }
    // layers 1..7 W: K=64 (KS=2), 4096 each, f16 (A = h is f16)
    for (int idx = gid; idx < 7 * 4096; idx += stride) {
        int l = idx >> 12, r = idx & 4095;
        int j = r & 7, lane = (r >> 3) & 63, rest = r >> 9;
        int ks = rest & 1, ct = rest >> 1;
        int quad = lane >> 4, m = lane & 15;
        wpack[8192 + idx] = f16bits(
            ldext(Ws, f32, (size_t)l * 4096 + (size_t)(ks * 32 + quad * 8 + j) * 64 + ct * 16 + m));
    }
    // lwB: 8 layers x 3072 (3 ct x 2 ks x 64 lanes x 8), f16
    for (int idx = gid; idx < LAYERS * 3072; idx += stride) {
        int l = idx / 3072, r = idx % 3072;
        int j = r & 7, lane = (r >> 3) & 63, rest = r >> 9;
        int ks = rest & 1, ct = rest >> 1;
        int quad = lane >> 4, m = lane & 15;
        int col = ct * 16 + m;
        int k = l * 64 + ks * 32 + quad * 8 + j;
        wpack[36864 + idx] = (col < OUT_DIM)
            ? f16bits(ldext(lin_w, f32, (size_t)k * OUT_DIM + col)) : (unsigned short)0;
    }
}

// ---------- phase 1: LDS counting-sort append into per-bucket FIFOs ----------
__global__ __launch_bounds__(256) void bucket1_kernel(const void* ei_raw, const int* __restrict__ flags,
                                                      int* __restrict__ gcur, int* __restrict__ fifo) {
    __shared__ int lhist[NBUK];
    __shared__ int lbase[NBUK];
    bool is64 = flags[1] != 0;
    int t = threadIdx.x;
    for (int i = t; i < NBUK; i += 256) lhist[i] = 0;
    __syncthreads();
    int e0 = blockIdx.x * S1_EPB;
    int rec[8], bk[8], loff[8];
#pragma unroll
    for (int j = 0; j < 8; j++) {
        int e = e0 + j * 256 + t;
        bk[j] = -1;
        if (e < N_EDGES) {
            int s = load_edge(ei_raw, is64, e);
            int d = load_edge(ei_raw, is64, (long long)N_EDGES + e);
            int b = d >> 9;
            bk[j] = b;
            rec[j] = ((d & 511) << 17) | s;
            loff[j] = atomicAdd(&lhist[b], 1);
        }
    }
    __syncthreads();
    for (int i = t; i < NBUK; i += 256)
        lbase[i] = (lhist[i] > 0) ? atomicAdd(&gcur[i], lhist[i]) : 0;
    __syncthreads();
#pragma unroll
    for (int j = 0; j < 8; j++) {
        if (bk[j] >= 0) {
            int idx = lbase[bk[j]] + loff[j];
            if (idx < BUK_CAP) fifo[bk[j] * BUK_CAP + idx] = rec[j];
        }
    }
}

// ---------- degree + dis from FIFO (LDS counters; fused former calc_dis) ----------
__global__ __launch_bounds__(256) void deg_fifo_kernel(const int* __restrict__ gcur,
                                                       const int* __restrict__ fifo,
                                                       int* __restrict__ deg,
                                                       float* __restrict__ dis) {
    __shared__ int ldeg[512];
    int b = blockIdx.x, t = threadIdx.x;
    ldeg[t] = 0;
    ldeg[t + 256] = 0;
    __syncthreads();
    int cnt = min(gcur[b], BUK_CAP);
    for (int i = t; i < cnt; i += 256)
        atomicAdd(&ldeg[fifo[b * BUK_CAP + i] >> 17], 1);
    __syncthreads();
    int n0 = b * 512 + t;
    if (n0 < N_NODES) {
        int d = ldeg[t];
        deg[n0] = d;
        dis[n0] = rsqrtf((float)(d + 1));  // +1 self-loop
    }
    if (n0 + 256 < N_NODES) {
        int d = ldeg[t + 256];
        deg[n0 + 256] = d;
        dis[n0 + 256] = rsqrtf((float)(d + 1));
    }
}

// exclusive scan of deg -> row (3-kernel, 1024 elems/block)
__global__ __launch_bounds__(256) void scan1_kernel(const int* __restrict__ deg, int* __restrict__ row,
                                                    int* __restrict__ bsums) {
    __shared__ int sd[256];
    int t = threadIdx.x;
    int base = blockIdx.x * 1024 + t * 4;
    int v[4];
#pragma unroll
    for (int j = 0; j < 4; j++) {
        int idx = base + j;
        v[j] = (idx < N_NODES) ? deg[idx] : 0;
    }
    int s4 = v[0] + v[1] + v[2] + v[3];
    sd[t] = s4;
    __syncthreads();
    for (int off = 1; off < 256; off <<= 1) {
        int x = (t >= off) ? sd[t - off] : 0;
        __syncthreads();
        sd[t] += x;
        __syncthreads();
    }
    int run = sd[t] - s4;  // exclusive
#pragma unroll
    for (int j = 0; j < 4; j++) {
        int idx = base + j;
        if (idx < N_NODES) row[idx] = run;
        run += v[j];
    }
    if (t == 255) bsums[blockIdx.x] = sd[255];
}

__global__ void scan2_kernel(int* bsums) {
    __shared__ int sd[128];
    int t = threadIdx.x;
    int v = (t < SCAN_NB) ? bsums[t] : 0;
    sd[t] = v;
    __syncthreads();
    for (int off = 1; off < 128; off <<= 1) {
        int x = (t >= off) ? sd[t - off] : 0;
        __syncthreads();
        sd[t] += x;
        __syncthreads();
    }
    if (t < SCAN_NB) bsums[t] = sd[t] - v;  // exclusive block offsets
}

__global__ __launch_bounds__(256) void scan3_kernel(int* __restrict__ row, const int* __restrict__ bsums) {
    int i = blockIdx.x * 256 + threadIdx.x;
    if (i < N_NODES) row[i] += bsums[i >> 10];
    if (i == 0) row[N_NODES] = N_EDGES;
}

// ---------- phase 2: per-bucket scatter to final CSR with LDS cursors ----------
__global__ __launch_bounds__(256) void bucket2_kernel(const int* __restrict__ gcur,
                                                      const int* __restrict__ fifo,
                                                      const int* __restrict__ row,
                                                      int* __restrict__ csr_src) {
    __shared__ int lcur[512];
    int b = blockIdx.x, t = threadIdx.x;
    int n0 = b * 512 + t;
    lcur[t] = row[min(n0, N_NODES)];
    lcur[t + 256] = row[min(n0 + 256, N_NODES)];
    __syncthreads();
    int cnt = min(gcur[b], BUK_CAP);
    for (int i = t; i < cnt; i += 256) {
        int r = fifo[b * BUK_CAP + i];
        int pos = atomicAdd(&lcur[r >> 17], 1);
        csr_src[pos] = r & 0x1FFFF;
    }
}

// ---------- layer-0 MFMA matmul: t0a (f16, FULL 128B rows, dis-prescaled) = dis .* (x @ W0) ----------
// rows >= N_NODES (pad rows incl. ZROW) written as exact ZERO.
__global__ __launch_bounds__(256) void mm0_kernel(const void* __restrict__ x,
                                                  const int* __restrict__ flags,
                                                  const unsigned short* __restrict__ wW,
                                                  const float* __restrict__ dis,
                                                  __half* __restrict__ t0) {
    constexpr int KS = 4, K = 128;
    int wave = threadIdx.x >> 6, lane = threadIdx.x & 63;
    int quad = lane >> 4, m = lane & 15;
    int nb = blockIdx.x * 64 + wave * 16;
    int ra = nb + m;
    if (ra > N_NODES - 1) ra = N_NODES - 1;  // clamp tail (avoids OOB read)
    short8 a[KS];
    if (flags[0]) {
        const float* xr = (const float*)x + (size_t)ra * K + quad * 8;
#pragma unroll
        for (int ks = 0; ks < KS; ks++) {
            float4 f0 = *(const float4*)(xr + ks * 32);
            float4 f1 = *(const float4*)(xr + ks * 32 + 4);
            short8 v;
            v[0] = (short)bf16bits(f0.x); v[1] = (short)bf16bits(f0.y);
            v[2] = (short)bf16bits(f0.z); v[3] = (short)bf16bits(f0.w);
            v[4] = (short)bf16bits(f1.x); v[5] = (short)bf16bits(f1.y);
            v[6] = (short)bf16bits(f1.z); v[7] = (short)bf16bits(f1.w);
            a[ks] = v;
        }
    } else {
        const short* hrow = (const short*)x + (size_t)ra * K + quad * 8;
#pragma unroll
        for (int ks = 0; ks < KS; ks++) a[ks] = *(const short8*)(hrow + ks * 32);
    }
    float dr[4];
#pragma unroll
    for (int r = 0; r < 4; r++) {
        int rw = nb + quad * 4 + r;
        dr[r] = (rw < N_NODES) ? dis[rw] : 0.f;  // pad rows -> exact zero
    }
#pragma unroll
    for (int ct = 0; ct < 4; ct++) {
        float4v acc = (float4v){0.f, 0.f, 0.f, 0.f};
#pragma unroll
        for (int ks = 0; ks < KS; ks++) {
            short8 b = *(const short8*)(wW + ((ct * KS + ks) * 64 + lane) * 8);
            acc = __builtin_amdgcn_mfma_f32_16x16x32_bf16(a[ks], b, acc, 0, 0, 0);
        }
#pragma unroll
        for (int r = 0; r < 4; r++) {
            t0[(size_t)(nb + quad * 4 + r) * 64 + ct * 16 + m] =
                __float2half(acc[r] * dr[r]);
        }
    }
}

// ---------- fused per-layer kernel: agg(l) -> h_l in LDS -> mm(l+1) + JK(l) ----------
// R11: phase-A pipeline deepened 3 -> 4 states (12 loads in flight/wave, +33% MLP) —
// testing whether phase A is still latency-bound (43us, 2.9TB/s L3 service) or at
// the L3 random-service roofline. All else identical to R10.
template <int MODE>
__global__ __launch_bounds__(512, 4) void fused_kernel(const __half* __restrict__ t0_in,
                                                       __half* __restrict__ t0_out,
                                                       const int* __restrict__ row,
                                                       const int* __restrict__ csr_src,
                                                       const float* __restrict__ bsf,   // layer-l bias, 64 f32
                                                       const unsigned short* __restrict__ wW,  // W_{l+1}
                                                       const unsigned short* __restrict__ wJ,  // lwB_l
                                                       float* __restrict__ out_acc,
                                                       const void* __restrict__ lin_b,
                                                       const int* __restrict__ flags,
                                                       void* __restrict__ d_out) {
    __shared__ int lrow[FU_N + 1];
    __shared__ __align__(16) int lcsr[FU_CAP + 32];
    __shared__ __align__(16) __half hbuf[FU_N * HB_S];
    int t = threadIdx.x;
    int nb = blockIdx.x * FU_N;

    for (int i = t; i <= FU_N; i += 512) {
        int n = nb + i;
        lrow[i] = row[n > N_NODES ? N_NODES : n];
    }
    __syncthreads();
    int rs0 = lrow[0];
    int cnt_raw = lrow[FU_N] - rs0;
    int cnt = min(cnt_raw, FU_CAP);

    int wave = t >> 6, lane = t & 63;
    for (int c = wave; c * 256 < cnt; c += 8) {
        const int* gsrc = csr_src + rs0 + c * 256 + lane * 4;
        __builtin_amdgcn_global_load_lds(
            (const __attribute__((address_space(1))) unsigned int*)gsrc,
            (__attribute__((address_space(3))) unsigned int*)&lcsr[4 + c * 256],
            16, 0, 0);
    }
    asm volatile("s_waitcnt vmcnt(0)" ::: "memory");
    __syncthreads();

    int g = lane >> 3, p = lane & 7;
    unsigned po = (unsigned)(p << 4);
    const __half2 h2zero = __floats2half2_rn(0.f, 0.f);

    if (cnt_raw <= FU_CAP) {
        uint4v Av0, Av1, Av2; int Ars, Are;
        uint4v Bv0, Bv1, Bv2; int Brs, Bre;
        uint4v Cv0, Cv1, Cv2; int Crs, Cre;
        uint4v Dv0, Dv1, Dv2; int Drs, Dre;

#define AGG_ISSUE(P, v0, v1, v2, rs_, re_)                                      \
        do {                                                                    \
            int nl_ = wave * 8 + (P);                                           \
            int node_ = nb + nl_;                                               \
            bool valid_ = node_ < N_NODES;                                      \
            rs_ = valid_ ? lrow[nl_] : 0;                                       \
            re_ = valid_ ? lrow[nl_ + 1] : 0;                                   \
            int b_ = max(rs_ - rs0, 0) + g;                                     \
            int se0_ = lcsr[b_ + 3];   /* edge rs+g-1  */                       \
            int se1_ = lcsr[b_ + 11];  /* edge rs+g+7  */                       \
            int se2_ = lcsr[b_ + 19];  /* edge rs+g+15 */                       \
            se0_ = (g == 0) ? (valid_ ? node_ : ZROW)                           \
                            : ((rs_ + g - 1 < re_) ? se0_ : ZROW);              \
            se1_ = (rs_ + g + 7  < re_) ? se1_ : ZROW;                          \
            se2_ = (rs_ + g + 15 < re_) ? se2_ : ZROW;                          \
            v0 = gload16(t0_in, ((unsigned)se0_ << 7) | po);                    \
            v1 = gload16(t0_in, ((unsigned)se1_ << 7) | po);                    \
            v2 = gload16(t0_in, ((unsigned)se2_ << 7) | po);                    \
        } while (0)

#define AGG_CONSUME(P, v0, v1, v2, rs_, re_)                                    \
        do {                                                                    \
            int nl_ = wave * 8 + (P);                                           \
            int node_ = nb + nl_;                                               \
            bool valid_ = node_ < N_NODES;                                      \
            __half2 a0_ = __hadd2(__hadd2(u2h2(v0[0]), u2h2(v1[0])), u2h2(v2[0])); \
            __half2 a1_ = __hadd2(__hadd2(u2h2(v0[1]), u2h2(v1[1])), u2h2(v2[1])); \
            __half2 a2_ = __hadd2(__hadd2(u2h2(v0[2]), u2h2(v1[2])), u2h2(v2[2])); \
            __half2 a3_ = __hadd2(__hadd2(u2h2(v0[3]), u2h2(v1[3])), u2h2(v2[3])); \
            if (__builtin_expect(__any(re_ - rs_ > 23), 0)) {                   \
                for (int q_ = rs_ + 23 + g; q_ < re_; q_ += 8) {                \
                    int se_ = lcsr[4 + q_ - rs0];                               \
                    uint4 v_ = *(const uint4*)(t0_in + (size_t)se_ * 64 + p * 8);\
                    a0_ = __hadd2(a0_, u2h2(v_.x));                             \
                    a1_ = __hadd2(a1_, u2h2(v_.y));                             \
                    a2_ = __hadd2(a2_, u2h2(v_.z));                             \
                    a3_ = __hadd2(a3_, u2h2(v_.w));                             \
                }                                                               \
            }                                                                   \
            a0_ = __hadd2(a0_, u2h2(dppu<0x128>(h22u(a0_))));                   \
            a1_ = __hadd2(a1_, u2h2(dppu<0x128>(h22u(a1_))));                   \
            a2_ = __hadd2(a2_, u2h2(dppu<0x128>(h22u(a2_))));                   \
            a3_ = __hadd2(a3_, u2h2(dppu<0x128>(h22u(a3_))));                   \
            a0_ = __hadd2(a0_, u2h2(__shfl_xor(h22u(a0_), 16)));                \
            a1_ = __hadd2(a1_, u2h2(__shfl_xor(h22u(a1_), 16)));                \
            a2_ = __hadd2(a2_, u2h2(__shfl_xor(h22u(a2_), 16)));                \
            a3_ = __hadd2(a3_, u2h2(__shfl_xor(h22u(a3_), 16)));                \
            a0_ = __hadd2(a0_, u2h2(__shfl_xor(h22u(a0_), 32)));                \
            a1_ = __hadd2(a1_, u2h2(__shfl_xor(h22u(a1_), 32)));                \
            a2_ = __hadd2(a2_, u2h2(__shfl_xor(h22u(a2_), 32)));                \
            a3_ = __hadd2(a3_, u2h2(__shfl_xor(h22u(a3_), 32)));                \
            if (g == 0) {                                                       \
                float di_ = rsqrtf((float)(re_ - rs_ + 1));                     \
                const float* bb_ = bsf + p * 8;                                 \
                float f_[8];                                                    \
                f_[0] = __low2float(a0_); f_[1] = __high2float(a0_);            \
                f_[2] = __low2float(a1_); f_[3] = __high2float(a1_);            \
                f_[4] = __low2float(a2_); f_[5] = __high2float(a2_);            \
                f_[6] = __low2float(a3_); f_[7] = __high2float(a3_);            \
                _Pragma("unroll")                                               \
                for (int j_ = 0; j_ < 8; j_++)                                  \
                    f_[j_] = fmaxf(di_ * f_[j_] + bb_[j_], 0.f);                \
                uint4 pv_;                                                      \
                pv_.x = valid_ ? h22u(__floats2half2_rn(f_[0], f_[1])) : 0u;    \
                pv_.y = valid_ ? h22u(__floats2half2_rn(f_[2], f_[3])) : 0u;    \
                pv_.z = valid_ ? h22u(__floats2half2_rn(f_[4], f_[5])) : 0u;    \
                pv_.w = valid_ ? h22u(__floats2half2_rn(f_[6], f_[7])) : 0u;    \
                *(uint4*)(hbuf + (size_t)nl_ * HB_S + p * 8) = pv_;             \
            }                                                                   \
        } while (0)

        // 4-deep pipeline: P0..P7 -> states A,B,C,D,A,B,C,D; 12 loads in flight.
        AGG_ISSUE(0, Av0, Av1, Av2, Ars, Are);
        AGG_ISSUE(1, Bv0, Bv1, Bv2, Brs, Bre);
        AGG_ISSUE(2, Cv0, Cv1, Cv2, Crs, Cre);
        AGG_ISSUE(3, Dv0, Dv1, Dv2, Drs, Dre);
        WAITV(9); AGG_CONSUME(0, Av0, Av1, Av2, Ars, Are);
        AGG_ISSUE(4, Av0, Av1, Av2, Ars, Are);
        WAITV(9); AGG_CONSUME(1, Bv0, Bv1, Bv2, Brs, Bre);
        AGG_ISSUE(5, Bv0, Bv1, Bv2, Brs, Bre);
        WAITV(9); AGG_CONSUME(2, Cv0, Cv1, Cv2, Crs, Cre);
        AGG_ISSUE(6, Cv0, Cv1, Cv2, Crs, Cre);
        WAITV(9); AGG_CONSUME(3, Dv0, Dv1, Dv2, Drs, Dre);
        AGG_ISSUE(7, Dv0, Dv1, Dv2, Drs, Dre);
        WAITV(9); AGG_CONSUME(4, Av0, Av1, Av2, Ars, Are);
        WAITV(6); AGG_CONSUME(5, Bv0, Bv1, Bv2, Brs, Bre);
        WAITV(3); AGG_CONSUME(6, Cv0, Cv1, Cv2, Crs, Cre);
        WAITV(0); AGG_CONSUME(7, Dv0, Dv1, Dv2, Drs, Dre);
#undef AGG_ISSUE
#undef AGG_CONSUME
    } else {
        // slow path: staged-LDS overflow (block-uniform, essentially never taken)
        for (int pass = 0; pass < 8; pass++) {
            int nl = wave * 8 + pass;
            int node = nb + nl;
            bool valid = node < N_NODES;
            int rs = valid ? lrow[nl] : 0;
            int re = valid ? lrow[nl + 1] : 0;
            __half2 a2[4];
#pragma unroll
            for (int r = 0; r < 4; r++) a2[r] = h2zero;
            if (valid && g == 0) {
                uint4 v = *(const uint4*)(t0_in + (size_t)node * 64 + p * 8);
                a2[0] = __hadd2(a2[0], u2h2(v.x));
                a2[1] = __hadd2(a2[1], u2h2(v.y));
                a2[2] = __hadd2(a2[2], u2h2(v.z));
                a2[3] = __hadd2(a2[3], u2h2(v.w));
            }
            for (int e = rs + g; e < re; e += 8) {
                int idx = e - rs0;
                int se = (idx < FU_CAP) ? lcsr[4 + idx] : csr_src[e];
                uint4 v = *(const uint4*)(t0_in + (size_t)se * 64 + p * 8);
                a2[0] = __hadd2(a2[0], u2h2(v.x));
                a2[1] = __hadd2(a2[1], u2h2(v.y));
                a2[2] = __hadd2(a2[2], u2h2(v.z));
                a2[3] = __hadd2(a2[3], u2h2(v.w));
            }
#pragma unroll
            for (int st = 8; st <= 32; st <<= 1) {
#pragma unroll
                for (int r = 0; r < 4; r++)
                    a2[r] = __hadd2(a2[r], u2h2(__shfl_xor(h22u(a2[r]), st)));
            }
            if (g == 0) {
                float di = rsqrtf((float)(re - rs + 1));
                const float* bb = bsf + p * 8;
                float a[8];
#pragma unroll
                for (int r = 0; r < 4; r++) {
                    a[2 * r]     = __low2float(a2[r]);
                    a[2 * r + 1] = __high2float(a2[r]);
                }
#pragma unroll
                for (int j = 0; j < 8; j++) a[j] = fmaxf(di * a[j] + bb[j], 0.f);
                uint4 pv;
                pv.x = valid ? h22u(__floats2half2_rn(a[0], a[1])) : 0u;
                pv.y = valid ? h22u(__floats2half2_rn(a[2], a[3])) : 0u;
                pv.z = valid ? h22u(__floats2half2_rn(a[4], a[5])) : 0u;
                pv.w = valid ? h22u(__floats2half2_rn(a[6], a[7])) : 0u;
                *(uint4*)(hbuf + (size_t)nl * HB_S + p * 8) = pv;
            }
        }
    }
    __syncthreads();

    // ---------- phase B: mm(l+1) + JK(l) from LDS hbuf ----------
    int quad = lane >> 4, m = lane & 15;
    int tile = wave & 3;
    int loc0 = tile * 16;
    if (MODE == 2 && wave >= 4) return;  // waves 4-7 idle in final layer
    short8 a0 = *(const short8*)(hbuf + (size_t)(loc0 + m) * HB_S + quad * 8);
    short8 a1 = *(const short8*)(hbuf + (size_t)(loc0 + m) * HB_S + quad * 8 + 32);
    if (MODE != 2 && wave < 4) {
        // t0_out = dis .* (h @ W_{l+1}); pad rows exact zero
        float dr[4];
#pragma unroll
        for (int r = 0; r < 4; r++) {
            int rl = loc0 + quad * 4 + r;
            float di = rsqrtf((float)(lrow[rl + 1] - lrow[rl] + 1));
            dr[r] = (nb + rl < N_NODES) ? di : 0.f;
        }
#pragma unroll
        for (int ct = 0; ct < 4; ct++) {
            float4v acc = (float4v){0.f, 0.f, 0.f, 0.f};
            short8 b0 = *(const short8*)(wW + ((ct * 2 + 0) * 64 + lane) * 8);
            short8 b1 = *(const short8*)(wW + ((ct * 2 + 1) * 64 + lane) * 8);
            acc = __builtin_amdgcn_mfma_f32_16x16x32_f16(
                __builtin_bit_cast(half8, a0), __builtin_bit_cast(half8, b0), acc, 0, 0, 0);
            acc = __builtin_amdgcn_mfma_f32_16x16x32_f16(
                __builtin_bit_cast(half8, a1), __builtin_bit_cast(half8, b1), acc, 0, 0, 0);
#pragma unroll
            for (int r = 0; r < 4; r++) {
                t0_out[(size_t)(nb + loc0 + quad * 4 + r) * 64 + ct * 16 + m] =
                    __float2half(acc[r] * dr[r]);
            }
        }
    } else {
        // JK: out_acc (MODE 0 '=', MODE 1 '+=') or final output (MODE 2)
        bool f32o = (MODE == 2) && (flags[0] != 0);
#pragma unroll
        for (int ct = 0; ct < 3; ct++) {
            float4v j = (float4v){0.f, 0.f, 0.f, 0.f};
            short8 b0 = *(const short8*)(wJ + ((ct * 2 + 0) * 64 + lane) * 8);
            short8 b1 = *(const short8*)(wJ + ((ct * 2 + 1) * 64 + lane) * 8);
            j = __builtin_amdgcn_mfma_f32_16x16x32_f16(
                __builtin_bit_cast(half8, a0), __builtin_bit_cast(half8, b0), j, 0, 0, 0);
            j = __builtin_amdgcn_mfma_f32_16x16x32_f16(
                __builtin_bit_cast(half8, a1), __builtin_bit_cast(half8, b1), j, 0, 0, 0);
            int col = ct * 16 + m;
            if (col < OUT_DIM) {
                float lb = (MODE == 2) ? ldext(lin_b, flags[0] != 0, col) : 0.f;
#pragma unroll
                for (int r = 0; r < 4; r++) {
                    int gw = nb + loc0 + quad * 4 + r;
                    if (gw < N_NODES) {
                        size_t o = (size_t)gw * OUT_DIM + col;
                        if (MODE == 0) out_acc[o] = j[r];
                        else if (MODE == 1) out_acc[o] += j[r];
                        else {
                            float v = out_acc[o] + j[r] + lb;
                            if (f32o) ((float*)d_out)[o] = v;
                            else ((__hip_bfloat16*)d_out)[o] = __float2bfloat16(v);
                        }
                    }
                }
            }
        }
    }
}

extern "C" void kernel_launch(void* const* d_in, const int* in_sizes, int n_in,
                              void* d_out, int out_size, void* d_ws, size_t ws_size,
                              hipStream_t stream) {
    const void* x     = d_in[0];
    const void* W0    = d_in[1];
    const void* Ws    = d_in[2];
    const void* bs    = d_in[3];
    const void* lin_w = d_in[4];
    const void* lin_b = d_in[5];
    const void* ei    = d_in[6];

    size_t off = 0;
    auto alloc = [&](size_t bytes) -> void* {
        void* p = (char*)d_ws + off;
        off += (bytes + 511) & ~(size_t)511;
        return p;
    };
    int*   flags   = (int*)alloc(512);
    float* dis     = (float*)alloc((size_t)(N_NODES + 64) * 4);
    int*   deg     = (int*)alloc((size_t)N_NODES * 4);
    int*   row     = (int*)alloc((size_t)(N_NODES + 1) * 4);
    int*   bsums   = (int*)alloc(128 * 4);
    int*   gcur    = (int*)alloc((size_t)NBUK * 4);
    int*   fifo    = (int*)alloc((size_t)NBUK * BUK_CAP * 4);   // 9.4 MB
    int*   csr_src = (int*)alloc((size_t)N_EDGES * 4);
    __half* t0a = (__half*)alloc((size_t)(N_NODES + 64) * HID * 2);  // 12.8MB full rows
    __half* t0b = (__half*)alloc((size_t)(N_NODES + 64) * HID * 2);  // double buffer
    float* out_acc = (float*)alloc((size_t)N_NODES * OUT_DIM * 4);
    float* bsf     = (float*)alloc((size_t)LAYERS * HID * 4);
    unsigned short* wpack = (unsigned short*)alloc((size_t)61440 * 2);

    const int nblkN  = (N_NODES + 255) / 256;
    const int nblkS1 = (N_EDGES + S1_EPB - 1) / S1_EPB;   // 782
    const int nblkMM = (N_NODES + 63) / 64;               // 1563
    const int nblkF  = (N_NODES + FU_N - 1) / FU_N;       // 1563

    detect_kernel<<<1, 64, 0, stream>>>(x, ei, flags, gcur);
    pack_params_kernel<<<80, 256, 0, stream>>>(bs, lin_w, W0, Ws, flags, bsf, wpack);
    bucket1_kernel<<<nblkS1, 256, 0, stream>>>(ei, flags, gcur, fifo);
    deg_fifo_kernel<<<NBUK, 256, 0, stream>>>(gcur, fifo, deg, dis);
    scan1_kernel<<<SCAN_NB, 256, 0, stream>>>(deg, row, bsums);
    scan2_kernel<<<1, 128, 0, stream>>>(bsums);
    scan3_kernel<<<nblkN, 256, 0, stream>>>(row, bsums);
    bucket2_kernel<<<NBUK, 256, 0, stream>>>(gcur, fifo, row, csr_src);

    const unsigned short* wJ0 = wpack + 36864;
    mm0_kernel<<<nblkMM, 256, 0, stream>>>(x, flags, wpack, dis, t0a);
    for (int l = 0; l < LAYERS; l++) {
        const __half* ti = (l & 1) ? t0b : t0a;
        __half*       to = (l & 1) ? t0a : t0b;
        const float*  bl = bsf + (size_t)l * HID;
        const unsigned short* wWn = wpack + 8192 + (size_t)l * 4096;  // W_{l+1} (l<7)
        const unsigned short* wJl = wJ0 + (size_t)l * 3072;           // lwB_l
        if (l == 0) {
            fused_kernel<0><<<nblkF, 512, 0, stream>>>(ti, to, row, csr_src, bl,
                                                       wWn, wJl, out_acc, lin_b, flags, d_out);
        } else if (l < 7) {
            fused_kernel<1><<<nblkF, 512, 0, stream>>>(ti, to, row, csr_src, bl,
                                                       wWn, wJl, out_acc, lin_b, flags, d_out);
        } else {
            fused_kernel<2><<<nblkF, 512, 0, stream>>>(ti, to, row, csr_src, bl,
                                                       wpack + 8192, wJl, out_acc, lin_b, flags, d_out);
        }
    }
}

// Round 12
// 492.983 us; speedup vs baseline: 1.0596x; 1.0596x over previous
//
#include <hip/hip_runtime.h>
#include <hip/hip_bf16.h>
#include <hip/hip_fp16.h>

#define N_NODES 100000
#define N_EDGES 1600000
#define HID     64
#define LAYERS  8
#define OUT_DIM 40
#define SCAN_NB 98   // ceil(100000/1024)
#define ZROW    N_NODES  // guaranteed-zero row in t0 (pad rows written 0 every layer)
#define NBUK    196      // ceil(100000/512) buckets of 512 nodes
#define BUK_CAP 12000    // avg 8163/bucket -> huge sigma headroom
#define S1_EPB  2048     // edges per bucket1 block (256 thr x 8)
#define FU_N    64       // nodes per fused block
#define FU_CAP  2048     // staged csr entries (mean 1024, +32 sigma), 8KB LDS
#define HB_S    72       // hbuf row stride in halves (64 + 8 pad: 2-way banks, 16B aligned)

typedef __attribute__((ext_vector_type(8))) short short8;
typedef __attribute__((ext_vector_type(8))) _Float16 half8;
typedef __attribute__((ext_vector_type(4))) float float4v;
typedef __attribute__((ext_vector_type(4))) unsigned int uint4v;

// ---------- runtime environment hedges ----------
// flags[0] = 1 if feature inputs are float32 (else bf16)
// flags[1] = 1 if edge_index is int64 (else int32)
__device__ inline float ldext(const void* p, bool f32, size_t i) {
    return f32 ? ((const float*)p)[i]
               : __bfloat162float(((const __hip_bfloat16*)p)[i]);
}
__device__ inline int load_edge(const void* raw, bool is64, long long idx) {
    return is64 ? (int)((const long long*)raw)[idx] : ((const int*)raw)[idx];
}
__device__ inline unsigned short bf16bits(float v) {
    union { __hip_bfloat16 b; unsigned short u; } a;
    a.b = __float2bfloat16(v);
    return a.u;
}
__device__ inline unsigned short f16bits(float v) {
    union { __half h; unsigned short u; } a;
    a.h = __float2half_rn(v);
    return a.u;
}
__device__ inline __half2 u2h2(unsigned u) {
    union { unsigned u; __half2 h; } x; x.u = u; return x.h;
}
__device__ inline unsigned h22u(__half2 h) {
    union { unsigned u; __half2 h; } x; x.h = h; return x.u;
}

// DPP lane-rotation move (VALU pipe). 0x128 = row_ror:8 — rotation by 8 within a
// 16-lane row == pairwise xor-8 exchange (valid for commutative sum).
template <int CTRL>
__device__ inline unsigned dppu(unsigned v) {
    return (unsigned)__builtin_amdgcn_update_dpp((int)v, (int)v, CTRL, 0xF, 0xF, false);
}

// inline-asm 16B gather: SGPR base (wave-uniform t0 ptr) + 32b per-lane voffset.
// asm volatile ordering pins the 3-deep pipeline at ISA level.
__device__ inline uint4v gload16(const __half* base, unsigned voff) {
    uint4v d;
    asm volatile("global_load_dwordx4 %0, %1, %2"
                 : "=v"(d)
                 : "v"(voff), "s"((unsigned long long)base));
    return d;
}
// counted wait + scheduler fence (rule #18: VALU consumers must not hoist above it)
#define WAITV(N) do { asm volatile("s_waitcnt vmcnt(" #N ")" ::: "memory"); \
                      __builtin_amdgcn_sched_barrier(0); } while (0)

// also zeroes gcur (fused former zero_int_kernel)
__global__ void detect_kernel(const void* x, const void* ei, int* flags, int* gcur) {
    int t = threadIdx.x;  // 64 threads
    for (int i = t; i < NBUK; i += 64) gcur[i] = 0;
    float v = fabsf(__bfloat162float(((const __hip_bfloat16*)x)[t]));
    bool inband = (v >= 0.00390625f && v <= 16.0f);
    unsigned long long m = __ballot(inband);
    if (t == 0) {
        flags[0] = (__popcll(m) < 48) ? 1 : 0;  // fp32 misread as bf16 -> ~33/64 in band
        const int* e32 = (const int*)ei;
        flags[1] = ((e32[1] | e32[3] | e32[5] | e32[7]) == 0) ? 1 : 0;
    }
}

// pack: bias (fp32); W0 as bf16 MFMA B-frags; W1..7 and lwB as f16 MFMA B-frags.
__global__ __launch_bounds__(256) void pack_params_kernel(const void* bs, const void* lin_w,
                                                          const void* W0, const void* Ws,
                                                          const int* __restrict__ flags,
                                                          float* __restrict__ bsf,
                                                          unsigned short* __restrict__ wpack) {
    bool f32 = flags[0] != 0;
    int gid = blockIdx.x * 256 + threadIdx.x;
    int stride = gridDim.x * 256;
    for (int idx = gid; idx < LAYERS * HID; idx += stride) bsf[idx] = ldext(bs, f32, idx);
    // layer 0 W: K=128 (KS=4), 8192 elements, bf16 (A = x is bf16)
    for (int idx = gid; idx < 8192; idx += stride) {
        int j = idx & 7, lane = (idx >> 3) & 63, rest = idx >> 9;
        int ks = rest & 3, ct = rest >> 2;
        int quad = lane >> 4, m = lane & 15;
        wpack[idx] = bf16bits(ldext(W0, f32, (size_t)(ks * 32 + quad * 8 + j) * 64 + ct * 16 + m));
    }
    // layers 1..7 W: K=64 (KS=2), 4096 each, f16 (A = h is f16)
    for (int idx = gid; idx < 7 * 4096; idx += stride) {
        int l = idx >> 12, r = idx & 4095;
        int j = r & 7, lane = (r >> 3) & 63, rest = r >> 9;
        int ks = rest & 1, ct = rest >> 1;
        int quad = lane >> 4, m = lane & 15;
        wpack[8192 + idx] = f16bits(
            ldext(Ws, f32, (size_t)l * 4096 + (size_t)(ks * 32 + quad * 8 + j) * 64 + ct * 16 + m));
    }
    // lwB: 8 layers x 3072 (3 ct x 2 ks x 64 lanes x 8), f16
    for (int idx = gid; idx < LAYERS * 3072; idx += stride) {
        int l = idx / 3072, r = idx % 3072;
        int j = r & 7, lane = (r >> 3) & 63, rest = r >> 9;
        int ks = rest & 1, ct = rest >> 1;
        int quad = lane >> 4, m = lane & 15;
        int col = ct * 16 + m;
        int k = l * 64 + ks * 32 + quad * 8 + j;
        wpack[36864 + idx] = (col < OUT_DIM)
            ? f16bits(ldext(lin_w, f32, (size_t)k * OUT_DIM + col)) : (unsigned short)0;
    }
}

// ---------- phase 1: LDS counting-sort append into per-bucket FIFOs ----------
__global__ __launch_bounds__(256) void bucket1_kernel(const void* ei_raw, const int* __restrict__ flags,
                                                      int* __restrict__ gcur, int* __restrict__ fifo) {
    __shared__ int lhist[NBUK];
    __shared__ int lbase[NBUK];
    bool is64 = flags[1] != 0;
    int t = threadIdx.x;
    for (int i = t; i < NBUK; i += 256) lhist[i] = 0;
    __syncthreads();
    int e0 = blockIdx.x * S1_EPB;
    int rec[8], bk[8], loff[8];
#pragma unroll
    for (int j = 0; j < 8; j++) {
        int e = e0 + j * 256 + t;
        bk[j] = -1;
        if (e < N_EDGES) {
            int s = load_edge(ei_raw, is64, e);
            int d = load_edge(ei_raw, is64, (long long)N_EDGES + e);
            int b = d >> 9;
            bk[j] = b;
            rec[j] = ((d & 511) << 17) | s;
            loff[j] = atomicAdd(&lhist[b], 1);
        }
    }
    __syncthreads();
    for (int i = t; i < NBUK; i += 256)
        lbase[i] = (lhist[i] > 0) ? atomicAdd(&gcur[i], lhist[i]) : 0;
    __syncthreads();
#pragma unroll
    for (int j = 0; j < 8; j++) {
        if (bk[j] >= 0) {
            int idx = lbase[bk[j]] + loff[j];
            if (idx < BUK_CAP) fifo[bk[j] * BUK_CAP + idx] = rec[j];
        }
    }
}

// ---------- degree + dis from FIFO (LDS counters; fused former calc_dis) ----------
__global__ __launch_bounds__(256) void deg_fifo_kernel(const int* __restrict__ gcur,
                                                       const int* __restrict__ fifo,
                                                       int* __restrict__ deg,
                                                       float* __restrict__ dis) {
    __shared__ int ldeg[512];
    int b = blockIdx.x, t = threadIdx.x;
    ldeg[t] = 0;
    ldeg[t + 256] = 0;
    __syncthreads();
    int cnt = min(gcur[b], BUK_CAP);
    for (int i = t; i < cnt; i += 256)
        atomicAdd(&ldeg[fifo[b * BUK_CAP + i] >> 17], 1);
    __syncthreads();
    int n0 = b * 512 + t;
    if (n0 < N_NODES) {
        int d = ldeg[t];
        deg[n0] = d;
        dis[n0] = rsqrtf((float)(d + 1));  // +1 self-loop
    }
    if (n0 + 256 < N_NODES) {
        int d = ldeg[t + 256];
        deg[n0 + 256] = d;
        dis[n0 + 256] = rsqrtf((float)(d + 1));
    }
}

// exclusive scan of deg -> row (3-kernel, 1024 elems/block)
__global__ __launch_bounds__(256) void scan1_kernel(const int* __restrict__ deg, int* __restrict__ row,
                                                    int* __restrict__ bsums) {
    __shared__ int sd[256];
    int t = threadIdx.x;
    int base = blockIdx.x * 1024 + t * 4;
    int v[4];
#pragma unroll
    for (int j = 0; j < 4; j++) {
        int idx = base + j;
        v[j] = (idx < N_NODES) ? deg[idx] : 0;
    }
    int s4 = v[0] + v[1] + v[2] + v[3];
    sd[t] = s4;
    __syncthreads();
    for (int off = 1; off < 256; off <<= 1) {
        int x = (t >= off) ? sd[t - off] : 0;
        __syncthreads();
        sd[t] += x;
        __syncthreads();
    }
    int run = sd[t] - s4;  // exclusive
#pragma unroll
    for (int j = 0; j < 4; j++) {
        int idx = base + j;
        if (idx < N_NODES) row[idx] = run;
        run += v[j];
    }
    if (t == 255) bsums[blockIdx.x] = sd[255];
}

__global__ void scan2_kernel(int* bsums) {
    __shared__ int sd[128];
    int t = threadIdx.x;
    int v = (t < SCAN_NB) ? bsums[t] : 0;
    sd[t] = v;
    __syncthreads();
    for (int off = 1; off < 128; off <<= 1) {
        int x = (t >= off) ? sd[t - off] : 0;
        __syncthreads();
        sd[t] += x;
        __syncthreads();
    }
    if (t < SCAN_NB) bsums[t] = sd[t] - v;  // exclusive block offsets
}

__global__ __launch_bounds__(256) void scan3_kernel(int* __restrict__ row, const int* __restrict__ bsums) {
    int i = blockIdx.x * 256 + threadIdx.x;
    if (i < N_NODES) row[i] += bsums[i >> 10];
    if (i == 0) row[N_NODES] = N_EDGES;
}

// ---------- phase 2: per-bucket scatter to final CSR with LDS cursors ----------
__global__ __launch_bounds__(256) void bucket2_kernel(const int* __restrict__ gcur,
                                                      const int* __restrict__ fifo,
                                                      const int* __restrict__ row,
                                                      int* __restrict__ csr_src) {
    __shared__ int lcur[512];
    int b = blockIdx.x, t = threadIdx.x;
    int n0 = b * 512 + t;
    lcur[t] = row[min(n0, N_NODES)];
    lcur[t + 256] = row[min(n0 + 256, N_NODES)];
    __syncthreads();
    int cnt = min(gcur[b], BUK_CAP);
    for (int i = t; i < cnt; i += 256) {
        int r = fifo[b * BUK_CAP + i];
        int pos = atomicAdd(&lcur[r >> 17], 1);
        csr_src[pos] = r & 0x1FFFF;
    }
}

// ---------- layer-0 MFMA matmul: t0a (f16, FULL 128B rows, dis-prescaled) = dis .* (x @ W0) ----------
// rows >= N_NODES (pad rows incl. ZROW) written as exact ZERO.
__global__ __launch_bounds__(256) void mm0_kernel(const void* __restrict__ x,
                                                  const int* __restrict__ flags,
                                                  const unsigned short* __restrict__ wW,
                                                  const float* __restrict__ dis,
                                                  __half* __restrict__ t0) {
    constexpr int KS = 4, K = 128;
    int wave = threadIdx.x >> 6, lane = threadIdx.x & 63;
    int quad = lane >> 4, m = lane & 15;
    int nb = blockIdx.x * 64 + wave * 16;
    int ra = nb + m;
    if (ra > N_NODES - 1) ra = N_NODES - 1;  // clamp tail (avoids OOB read)
    short8 a[KS];
    if (flags[0]) {
        const float* xr = (const float*)x + (size_t)ra * K + quad * 8;
#pragma unroll
        for (int ks = 0; ks < KS; ks++) {
            float4 f0 = *(const float4*)(xr + ks * 32);
            float4 f1 = *(const float4*)(xr + ks * 32 + 4);
            short8 v;
            v[0] = (short)bf16bits(f0.x); v[1] = (short)bf16bits(f0.y);
            v[2] = (short)bf16bits(f0.z); v[3] = (short)bf16bits(f0.w);
            v[4] = (short)bf16bits(f1.x); v[5] = (short)bf16bits(f1.y);
            v[6] = (short)bf16bits(f1.z); v[7] = (short)bf16bits(f1.w);
            a[ks] = v;
        }
    } else {
        const short* hrow = (const short*)x + (size_t)ra * K + quad * 8;
#pragma unroll
        for (int ks = 0; ks < KS; ks++) a[ks] = *(const short8*)(hrow + ks * 32);
    }
    float dr[4];
#pragma unroll
    for (int r = 0; r < 4; r++) {
        int rw = nb + quad * 4 + r;
        dr[r] = (rw < N_NODES) ? dis[rw] : 0.f;  // pad rows -> exact zero
    }
#pragma unroll
    for (int ct = 0; ct < 4; ct++) {
        float4v acc = (float4v){0.f, 0.f, 0.f, 0.f};
#pragma unroll
        for (int ks = 0; ks < KS; ks++) {
            short8 b = *(const short8*)(wW + ((ct * KS + ks) * 64 + lane) * 8);
            acc = __builtin_amdgcn_mfma_f32_16x16x32_bf16(a[ks], b, acc, 0, 0, 0);
        }
#pragma unroll
        for (int r = 0; r < 4; r++) {
            t0[(size_t)(nb + quad * 4 + r) * 64 + ct * 16 + m] =
                __float2half(acc[r] * dr[r]);
        }
    }
}

// ---------- fused per-layer kernel: agg(l) -> h_l in LDS -> mm(l+1) + JK(l) ----------
// R12 = R10 exactly (3-deep pipeline): R11's 4-deep test REGRESSED (43.4 -> 47.3us,
// occupancy 46 -> 36%) — phase A is at the memory-system random-gather service floor,
// not latency-bound. 3-deep is the measured optimum.
template <int MODE>
__global__ __launch_bounds__(512, 4) void fused_kernel(const __half* __restrict__ t0_in,
                                                       __half* __restrict__ t0_out,
                                                       const int* __restrict__ row,
                                                       const int* __restrict__ csr_src,
                                                       const float* __restrict__ bsf,   // layer-l bias, 64 f32
                                                       const unsigned short* __restrict__ wW,  // W_{l+1}
                                                       const unsigned short* __restrict__ wJ,  // lwB_l
                                                       float* __restrict__ out_acc,
                                                       const void* __restrict__ lin_b,
                                                       const int* __restrict__ flags,
                                                       void* __restrict__ d_out) {
    __shared__ int lrow[FU_N + 1];
    __shared__ __align__(16) int lcsr[FU_CAP + 32];
    __shared__ __align__(16) __half hbuf[FU_N * HB_S];
    int t = threadIdx.x;
    int nb = blockIdx.x * FU_N;

    for (int i = t; i <= FU_N; i += 512) {
        int n = nb + i;
        lrow[i] = row[n > N_NODES ? N_NODES : n];
    }
    __syncthreads();
    int rs0 = lrow[0];
    int cnt_raw = lrow[FU_N] - rs0;
    int cnt = min(cnt_raw, FU_CAP);

    int wave = t >> 6, lane = t & 63;
    for (int c = wave; c * 256 < cnt; c += 8) {
        const int* gsrc = csr_src + rs0 + c * 256 + lane * 4;
        __builtin_amdgcn_global_load_lds(
            (const __attribute__((address_space(1))) unsigned int*)gsrc,
            (__attribute__((address_space(3))) unsigned int*)&lcsr[4 + c * 256],
            16, 0, 0);
    }
    asm volatile("s_waitcnt vmcnt(0)" ::: "memory");
    __syncthreads();

    int g = lane >> 3, p = lane & 7;
    unsigned po = (unsigned)(p << 4);
    const __half2 h2zero = __floats2half2_rn(0.f, 0.f);

    if (cnt_raw <= FU_CAP) {
        uint4v Av0, Av1, Av2; int Ars, Are;
        uint4v Bv0, Bv1, Bv2; int Brs, Bre;
        uint4v Cv0, Cv1, Cv2; int Crs, Cre;

#define AGG_ISSUE(P, v0, v1, v2, rs_, re_)                                      \
        do {                                                                    \
            int nl_ = wave * 8 + (P);                                           \
            int node_ = nb + nl_;                                               \
            bool valid_ = node_ < N_NODES;                                      \
            rs_ = valid_ ? lrow[nl_] : 0;                                       \
            re_ = valid_ ? lrow[nl_ + 1] : 0;                                   \
            int b_ = max(rs_ - rs0, 0) + g;                                     \
            int se0_ = lcsr[b_ + 3];   /* edge rs+g-1  */                       \
            int se1_ = lcsr[b_ + 11];  /* edge rs+g+7  */                       \
            int se2_ = lcsr[b_ + 19];  /* edge rs+g+15 */                       \
            se0_ = (g == 0) ? (valid_ ? node_ : ZROW)                           \
                            : ((rs_ + g - 1 < re_) ? se0_ : ZROW);              \
            se1_ = (rs_ + g + 7  < re_) ? se1_ : ZROW;                          \
            se2_ = (rs_ + g + 15 < re_) ? se2_ : ZROW;                          \
            v0 = gload16(t0_in, ((unsigned)se0_ << 7) | po);                    \
            v1 = gload16(t0_in, ((unsigned)se1_ << 7) | po);                    \
            v2 = gload16(t0_in, ((unsigned)se2_ << 7) | po);                    \
        } while (0)

#define AGG_CONSUME(P, v0, v1, v2, rs_, re_)                                    \
        do {                                                                    \
            int nl_ = wave * 8 + (P);                                           \
            int node_ = nb + nl_;                                               \
            bool valid_ = node_ < N_NODES;                                      \
            __half2 a0_ = __hadd2(__hadd2(u2h2(v0[0]), u2h2(v1[0])), u2h2(v2[0])); \
            __half2 a1_ = __hadd2(__hadd2(u2h2(v0[1]), u2h2(v1[1])), u2h2(v2[1])); \
            __half2 a2_ = __hadd2(__hadd2(u2h2(v0[2]), u2h2(v1[2])), u2h2(v2[2])); \
            __half2 a3_ = __hadd2(__hadd2(u2h2(v0[3]), u2h2(v1[3])), u2h2(v2[3])); \
            if (__builtin_expect(__any(re_ - rs_ > 23), 0)) {                   \
                for (int q_ = rs_ + 23 + g; q_ < re_; q_ += 8) {                \
                    int se_ = lcsr[4 + q_ - rs0];                               \
                    uint4 v_ = *(const uint4*)(t0_in + (size_t)se_ * 64 + p * 8);\
                    a0_ = __hadd2(a0_, u2h2(v_.x));                             \
                    a1_ = __hadd2(a1_, u2h2(v_.y));                             \
                    a2_ = __hadd2(a2_, u2h2(v_.z));                             \
                    a3_ = __hadd2(a3_, u2h2(v_.w));                             \
                }                                                               \
            }                                                                   \
            a0_ = __hadd2(a0_, u2h2(dppu<0x128>(h22u(a0_))));                   \
            a1_ = __hadd2(a1_, u2h2(dppu<0x128>(h22u(a1_))));                   \
            a2_ = __hadd2(a2_, u2h2(dppu<0x128>(h22u(a2_))));                   \
            a3_ = __hadd2(a3_, u2h2(dppu<0x128>(h22u(a3_))));                   \
            a0_ = __hadd2(a0_, u2h2(__shfl_xor(h22u(a0_), 16)));                \
            a1_ = __hadd2(a1_, u2h2(__shfl_xor(h22u(a1_), 16)));                \
            a2_ = __hadd2(a2_, u2h2(__shfl_xor(h22u(a2_), 16)));                \
            a3_ = __hadd2(a3_, u2h2(__shfl_xor(h22u(a3_), 16)));                \
            a0_ = __hadd2(a0_, u2h2(__shfl_xor(h22u(a0_), 32)));                \
            a1_ = __hadd2(a1_, u2h2(__shfl_xor(h22u(a1_), 32)));                \
            a2_ = __hadd2(a2_, u2h2(__shfl_xor(h22u(a2_), 32)));                \
            a3_ = __hadd2(a3_, u2h2(__shfl_xor(h22u(a3_), 32)));                \
            if (g == 0) {                                                       \
                float di_ = rsqrtf((float)(re_ - rs_ + 1));                     \
                const float* bb_ = bsf + p * 8;                                 \
                float f_[8];                                                    \
                f_[0] = __low2float(a0_); f_[1] = __high2float(a0_);            \
                f_[2] = __low2float(a1_); f_[3] = __high2float(a1_);            \
                f_[4] = __low2float(a2_); f_[5] = __high2float(a2_);            \
                f_[6] = __low2float(a3_); f_[7] = __high2float(a3_);            \
                _Pragma("unroll")                                               \
                for (int j_ = 0; j_ < 8; j_++)                                  \
                    f_[j_] = fmaxf(di_ * f_[j_] + bb_[j_], 0.f);                \
                uint4 pv_;                                                      \
                pv_.x = valid_ ? h22u(__floats2half2_rn(f_[0], f_[1])) : 0u;    \
                pv_.y = valid_ ? h22u(__floats2half2_rn(f_[2], f_[3])) : 0u;    \
                pv_.z = valid_ ? h22u(__floats2half2_rn(f_[4], f_[5])) : 0u;    \
                pv_.w = valid_ ? h22u(__floats2half2_rn(f_[6], f_[7])) : 0u;    \
                *(uint4*)(hbuf + (size_t)nl_ * HB_S + p * 8) = pv_;             \
            }                                                                   \
        } while (0)

        AGG_ISSUE(0, Av0, Av1, Av2, Ars, Are);
        AGG_ISSUE(1, Bv0, Bv1, Bv2, Brs, Bre);
        AGG_ISSUE(2, Cv0, Cv1, Cv2, Crs, Cre);
        WAITV(6); AGG_CONSUME(0, Av0, Av1, Av2, Ars, Are);
        AGG_ISSUE(3, Av0, Av1, Av2, Ars, Are);
        WAITV(6); AGG_CONSUME(1, Bv0, Bv1, Bv2, Brs, Bre);
        AGG_ISSUE(4, Bv0, Bv1, Bv2, Brs, Bre);
        WAITV(6); AGG_CONSUME(2, Cv0, Cv1, Cv2, Crs, Cre);
        AGG_ISSUE(5, Cv0, Cv1, Cv2, Crs, Cre);
        WAITV(6); AGG_CONSUME(3, Av0, Av1, Av2, Ars, Are);
        AGG_ISSUE(6, Av0, Av1, Av2, Ars, Are);
        WAITV(6); AGG_CONSUME(4, Bv0, Bv1, Bv2, Brs, Bre);
        AGG_ISSUE(7, Bv0, Bv1, Bv2, Brs, Bre);
        WAITV(6); AGG_CONSUME(5, Cv0, Cv1, Cv2, Crs, Cre);
        WAITV(3); AGG_CONSUME(6, Av0, Av1, Av2, Ars, Are);
        WAITV(0); AGG_CONSUME(7, Bv0, Bv1, Bv2, Brs, Bre);
#undef AGG_ISSUE
#undef AGG_CONSUME
    } else {
        // slow path: staged-LDS overflow (block-uniform, essentially never taken)
        for (int pass = 0; pass < 8; pass++) {
            int nl = wave * 8 + pass;
            int node = nb + nl;
            bool valid = node < N_NODES;
            int rs = valid ? lrow[nl] : 0;
            int re = valid ? lrow[nl + 1] : 0;
            __half2 a2[4];
#pragma unroll
            for (int r = 0; r < 4; r++) a2[r] = h2zero;
            if (valid && g == 0) {
                uint4 v = *(const uint4*)(t0_in + (size_t)node * 64 + p * 8);
                a2[0] = __hadd2(a2[0], u2h2(v.x));
                a2[1] = __hadd2(a2[1], u2h2(v.y));
                a2[2] = __hadd2(a2[2], u2h2(v.z));
                a2[3] = __hadd2(a2[3], u2h2(v.w));
            }
            for (int e = rs + g; e < re; e += 8) {
                int idx = e - rs0;
                int se = (idx < FU_CAP) ? lcsr[4 + idx] : csr_src[e];
                uint4 v = *(const uint4*)(t0_in + (size_t)se * 64 + p * 8);
                a2[0] = __hadd2(a2[0], u2h2(v.x));
                a2[1] = __hadd2(a2[1], u2h2(v.y));
                a2[2] = __hadd2(a2[2], u2h2(v.z));
                a2[3] = __hadd2(a2[3], u2h2(v.w));
            }
#pragma unroll
            for (int st = 8; st <= 32; st <<= 1) {
#pragma unroll
                for (int r = 0; r < 4; r++)
                    a2[r] = __hadd2(a2[r], u2h2(__shfl_xor(h22u(a2[r]), st)));
            }
            if (g == 0) {
                float di = rsqrtf((float)(re - rs + 1));
                const float* bb = bsf + p * 8;
                float a[8];
#pragma unroll
                for (int r = 0; r < 4; r++) {
                    a[2 * r]     = __low2float(a2[r]);
                    a[2 * r + 1] = __high2float(a2[r]);
                }
#pragma unroll
                for (int j = 0; j < 8; j++) a[j] = fmaxf(di * a[j] + bb[j], 0.f);
                uint4 pv;
                pv.x = valid ? h22u(__floats2half2_rn(a[0], a[1])) : 0u;
                pv.y = valid ? h22u(__floats2half2_rn(a[2], a[3])) : 0u;
                pv.z = valid ? h22u(__floats2half2_rn(a[4], a[5])) : 0u;
                pv.w = valid ? h22u(__floats2half2_rn(a[6], a[7])) : 0u;
                *(uint4*)(hbuf + (size_t)nl * HB_S + p * 8) = pv;
            }
        }
    }
    __syncthreads();

    // ---------- phase B: mm(l+1) + JK(l) from LDS hbuf ----------
    int quad = lane >> 4, m = lane & 15;
    int tile = wave & 3;
    int loc0 = tile * 16;
    if (MODE == 2 && wave >= 4) return;  // waves 4-7 idle in final layer
    short8 a0 = *(const short8*)(hbuf + (size_t)(loc0 + m) * HB_S + quad * 8);
    short8 a1 = *(const short8*)(hbuf + (size_t)(loc0 + m) * HB_S + quad * 8 + 32);
    if (MODE != 2 && wave < 4) {
        // t0_out = dis .* (h @ W_{l+1}); pad rows exact zero
        float dr[4];
#pragma unroll
        for (int r = 0; r < 4; r++) {
            int rl = loc0 + quad * 4 + r;
            float di = rsqrtf((float)(lrow[rl + 1] - lrow[rl] + 1));
            dr[r] = (nb + rl < N_NODES) ? di : 0.f;
        }
#pragma unroll
        for (int ct = 0; ct < 4; ct++) {
            float4v acc = (float4v){0.f, 0.f, 0.f, 0.f};
            short8 b0 = *(const short8*)(wW + ((ct * 2 + 0) * 64 + lane) * 8);
            short8 b1 = *(const short8*)(wW + ((ct * 2 + 1) * 64 + lane) * 8);
            acc = __builtin_amdgcn_mfma_f32_16x16x32_f16(
                __builtin_bit_cast(half8, a0), __builtin_bit_cast(half8, b0), acc, 0, 0, 0);
            acc = __builtin_amdgcn_mfma_f32_16x16x32_f16(
                __builtin_bit_cast(half8, a1), __builtin_bit_cast(half8, b1), acc, 0, 0, 0);
#pragma unroll
            for (int r = 0; r < 4; r++) {
                t0_out[(size_t)(nb + loc0 + quad * 4 + r) * 64 + ct * 16 + m] =
                    __float2half(acc[r] * dr[r]);
            }
        }
    } else {
        // JK: out_acc (MODE 0 '=', MODE 1 '+=') or final output (MODE 2)
        bool f32o = (MODE == 2) && (flags[0] != 0);
#pragma unroll
        for (int ct = 0; ct < 3; ct++) {
            float4v j = (float4v){0.f, 0.f, 0.f, 0.f};
            short8 b0 = *(const short8*)(wJ + ((ct * 2 + 0) * 64 + lane) * 8);
            short8 b1 = *(const short8*)(wJ + ((ct * 2 + 1) * 64 + lane) * 8);
            j = __builtin_amdgcn_mfma_f32_16x16x32_f16(
                __builtin_bit_cast(half8, a0), __builtin_bit_cast(half8, b0), j, 0, 0, 0);
            j = __builtin_amdgcn_mfma_f32_16x16x32_f16(
                __builtin_bit_cast(half8, a1), __builtin_bit_cast(half8, b1), j, 0, 0, 0);
            int col = ct * 16 + m;
            if (col < OUT_DIM) {
                float lb = (MODE == 2) ? ldext(lin_b, flags[0] != 0, col) : 0.f;
#pragma unroll
                for (int r = 0; r < 4; r++) {
                    int gw = nb + loc0 + quad * 4 + r;
                    if (gw < N_NODES) {
                        size_t o = (size_t)gw * OUT_DIM + col;
                        if (MODE == 0) out_acc[o] = j[r];
                        else if (MODE == 1) out_acc[o] += j[r];
                        else {
                            float v = out_acc[o] + j[r] + lb;
                            if (f32o) ((float*)d_out)[o] = v;
                            else ((__hip_bfloat16*)d_out)[o] = __float2bfloat16(v);
                        }
                    }
                }
            }
        }
    }
}

extern "C" void kernel_launch(void* const* d_in, const int* in_sizes, int n_in,
                              void* d_out, int out_size, void* d_ws, size_t ws_size,
                              hipStream_t stream) {
    const void* x     = d_in[0];
    const void* W0    = d_in[1];
    const void* Ws    = d_in[2];
    const void* bs    = d_in[3];
    const void* lin_w = d_in[4];
    const void* lin_b = d_in[5];
    const void* ei    = d_in[6];

    size_t off = 0;
    auto alloc = [&](size_t bytes) -> void* {
        void* p = (char*)d_ws + off;
        off += (bytes + 511) & ~(size_t)511;
        return p;
    };
    int*   flags   = (int*)alloc(512);
    float* dis     = (float*)alloc((size_t)(N_NODES + 64) * 4);
    int*   deg     = (int*)alloc((size_t)N_NODES * 4);
    int*   row     = (int*)alloc((size_t)(N_NODES + 1) * 4);
    int*   bsums   = (int*)alloc(128 * 4);
    int*   gcur    = (int*)alloc((size_t)NBUK * 4);
    int*   fifo    = (int*)alloc((size_t)NBUK * BUK_CAP * 4);   // 9.4 MB
    int*   csr_src = (int*)alloc((size_t)N_EDGES * 4);
    __half* t0a = (__half*)alloc((size_t)(N_NODES + 64) * HID * 2);  // 12.8MB full rows
    __half* t0b = (__half*)alloc((size_t)(N_NODES + 64) * HID * 2);  // double buffer
    float* out_acc = (float*)alloc((size_t)N_NODES * OUT_DIM * 4);
    float* bsf     = (float*)alloc((size_t)LAYERS * HID * 4);
    unsigned short* wpack = (unsigned short*)alloc((size_t)61440 * 2);

    const int nblkN  = (N_NODES + 255) / 256;
    const int nblkS1 = (N_EDGES + S1_EPB - 1) / S1_EPB;   // 782
    const int nblkMM = (N_NODES + 63) / 64;               // 1563
    const int nblkF  = (N_NODES + FU_N - 1) / FU_N;       // 1563

    detect_kernel<<<1, 64, 0, stream>>>(x, ei, flags, gcur);
    pack_params_kernel<<<80, 256, 0, stream>>>(bs, lin_w, W0, Ws, flags, bsf, wpack);
    bucket1_kernel<<<nblkS1, 256, 0, stream>>>(ei, flags, gcur, fifo);
    deg_fifo_kernel<<<NBUK, 256, 0, stream>>>(gcur, fifo, deg, dis);
    scan1_kernel<<<SCAN_NB, 256, 0, stream>>>(deg, row, bsums);
    scan2_kernel<<<1, 128, 0, stream>>>(bsums);
    scan3_kernel<<<nblkN, 256, 0, stream>>>(row, bsums);
    bucket2_kernel<<<NBUK, 256, 0, stream>>>(gcur, fifo, row, csr_src);

    const unsigned short* wJ0 = wpack + 36864;
    mm0_kernel<<<nblkMM, 256, 0, stream>>>(x, flags, wpack, dis, t0a);
    for (int l = 0; l < LAYERS; l++) {
        const __half* ti = (l & 1) ? t0b : t0a;
        __half*       to = (l & 1) ? t0a : t0b;
        const float*  bl = bsf + (size_t)l * HID;
        const unsigned short* wWn = wpack + 8192 + (size_t)l * 4096;  // W_{l+1} (l<7)
        const unsigned short* wJl = wJ0 + (size_t)l * 3072;           // lwB_l
        if (l == 0) {
            fused_kernel<0><<<nblkF, 512, 0, stream>>>(ti, to, row, csr_src, bl,
                                                       wWn, wJl, out_acc, lin_b, flags, d_out);
        } else if (l < 7) {
            fused_kernel<1><<<nblkF, 512, 0, stream>>>(ti, to, row, csr_src, bl,
                                                       wWn, wJl, out_acc, lin_b, flags, d_out);
        } else {
            fused_kernel<2><<<nblkF, 512, 0, stream>>>(ti, to, row, csr_src, bl,
                                                       wpack + 8192, wJl, out_acc, lin_b, flags, d_out);
        }
    }
}